// Round 6
// baseline (211.549 us; speedup 1.0000x reference)
//
#include <hip/hip_runtime.h>

#define DD 128
#define KK 384
#define NG 512

typedef __attribute__((ext_vector_type(8))) short bf16x8;
typedef __attribute__((ext_vector_type(4))) float f32x4;

__device__ __forceinline__ float bf2f(unsigned short u) {
  return __uint_as_float(((unsigned int)u) << 16);
}
__device__ __forceinline__ unsigned short f2bf(float f) {
  unsigned int x = __float_as_uint(f);
  x += 0x7fffu + ((x >> 16) & 1u);
  return (unsigned short)(x >> 16);
}
__device__ __forceinline__ float fsigmoid(float v) {
  return 1.f / (1.f + __expf(-v));
}
__device__ __forceinline__ float ftanh(float v) {
  float t = __expf(2.f * v);
  return (t - 1.f) / (t + 1.f);
}

// zero counts/cursor/gcur + f32->bf16 convert of h,x + fused-weight build, one kernel.
__global__ void k_init(const float* __restrict__ h, const float* __restrict__ x,
                       unsigned short* __restrict__ hbf, unsigned short* __restrict__ xbf,
                       const float* __restrict__ Wg0, const float* __restrict__ Wg1,
                       const float* __restrict__ Wg2, const float* __restrict__ Wg3,
                       const float* __restrict__ Wl0, const float* __restrict__ Wl1,
                       const float* __restrict__ Wl2, const float* __restrict__ Wl3,
                       const float* __restrict__ Wr0, const float* __restrict__ Wr1,
                       const float* __restrict__ Wr2, const float* __restrict__ Wr3,
                       const float* __restrict__ bg0, const float* __restrict__ bg1,
                       const float* __restrict__ bg2, const float* __restrict__ bg3,
                       const float* __restrict__ bl0, const float* __restrict__ bl1,
                       const float* __restrict__ bl2, const float* __restrict__ bl3,
                       unsigned short* __restrict__ Ut, float* __restrict__ bias,
                       int* __restrict__ counts, int* __restrict__ cursor,
                       int* __restrict__ gcur, int n, int n128, int conv_items) {
  long gid = (long)blockIdx.x * blockDim.x + threadIdx.x;
  if (gid < conv_items) {
    int i = (int)gid * 4;
    ushort4 ho, xo;
    if (i < n128) {
      float4 hv = *(const float4*)(h + i);
      float4 xv = *(const float4*)(x + i);
      ho = make_ushort4(f2bf(hv.x), f2bf(hv.y), f2bf(hv.z), f2bf(hv.w));
      xo = make_ushort4(f2bf(xv.x), f2bf(xv.y), f2bf(xv.z), f2bf(xv.w));
    } else {
      ho = make_ushort4(0, 0, 0, 0);
      xo = make_ushort4(0, 0, 0, 0);
    }
    *(ushort4*)(hbf + i) = ho;
    *(ushort4*)(xbf + i) = xo;
    return;
  }
  gid -= conv_items;
  if (gid < NG * KK) {
    int id = (int)gid;
    int nn = id / KK, k = id % KK;
    int g = nn >> 7, c = nn & 127;
    const float* Wg = g == 0 ? Wg0 : g == 1 ? Wg1 : g == 2 ? Wg2 : Wg3;
    const float* Wl = g == 0 ? Wl0 : g == 1 ? Wl1 : g == 2 ? Wl2 : Wl3;
    const float* Wr = g == 0 ? Wr0 : g == 1 ? Wr1 : g == 2 ? Wr2 : Wr3;
    float v;
    if (k < 128)      v = Wg[k * DD + c] + Wr[k * DD + c];
    else if (k < 256) v = Wg[k * DD + c];
    else              v = Wl[(k - 256) * DD + c];
    Ut[(size_t)nn * KK + k] = f2bf(v);
    if (k == 0) {
      const float* bgp = g == 0 ? bg0 : g == 1 ? bg1 : g == 2 ? bg2 : bg3;
      const float* blp = g == 0 ? bl0 : g == 1 ? bl1 : g == 2 ? bl2 : bl3;
      bias[nn] = bgp[c] + blp[c];
    }
    return;
  }
  gid -= NG * KK;
  if (gid < n) counts[gid] = 0;
  else if (gid < 2 * (long)n) cursor[gid - n] = 0;
  else if (gid == 2 * (long)n) *gcur = 0;
}

__global__ void k_count(const int* __restrict__ dst, int* __restrict__ counts, int E) {
  int e = blockIdx.x * blockDim.x + threadIdx.x;
  if (e < E) atomicAdd(counts + dst[e], 1);
}

__global__ void k_partition(const int* __restrict__ counts, int* __restrict__ row_start,
                            int* __restrict__ gcur, int n) {
  int i = blockIdx.x * blockDim.x + threadIdx.x;
  int lane = threadIdx.x & 63;
  int v = (i < n) ? counts[i] : 0;
  int s = v;
#pragma unroll
  for (int off = 1; off < 64; off <<= 1) {
    int t = __shfl_up(s, off);
    if (lane >= off) s += t;
  }
  int total = __shfl(s, 63);
  int base = 0;
  if (lane == 63) base = atomicAdd(gcur, total);
  base = __shfl(base, 63);
  if (i < n) row_start[i] = base + s - v;
}

__global__ void k_scatter(const int* __restrict__ srcv, const int* __restrict__ dstv,
                          const int* __restrict__ row_start, int* __restrict__ cursor,
                          int* __restrict__ csr, int E) {
  int e = blockIdx.x * blockDim.x + threadIdx.x;
  if (e < E) {
    int d = dstv[e];
    int pos = row_start[d] + atomicAdd(cursor + d, 1);
    csr[pos] = srcv[e];
  }
}

__device__ __forceinline__ void gload16(const void* g, void* l) {
  __builtin_amdgcn_global_load_lds((__attribute__((address_space(1))) void*)(void*)g,
                                   (__attribute__((address_space(3))) void*)l, 16, 0, 0);
}

// Fused gather + GEMM + LSTM-gate + LayerNorm.
// BM=64, BN=512, 12 K-steps of BK=32. 512 threads = 8 waves, wave tile 64x64.
// LDS: A dbuf 2x8KB @0/8192, B dbuf 2x32KB @16384/49152 = 80KB -> 2 blocks/CU.
// A windows (64 K-cols) staged every 2 steps; uniform counted vmcnt(5).
__global__ __launch_bounds__(512, 4) void k_gemm_fused(
    const unsigned short* __restrict__ hbf, const unsigned short* __restrict__ xbf,
    unsigned short* __restrict__ aggbf, const unsigned short* __restrict__ Ut,
    const int* __restrict__ row_start, const int* __restrict__ counts,
    const int* __restrict__ csr,
    const float* __restrict__ bias, const float* __restrict__ cell,
    const float* __restrict__ gamma, const float* __restrict__ beta,
    float* __restrict__ out, int nrows) {
  __shared__ char lds[81920];
  const int m0 = blockIdx.x * 64;
  const int tid = threadIdx.x;
  const int w = tid >> 6, lane = tid & 63;
  const int l15 = lane & 15, rg = lane >> 4;

  // ---- staging helpers (LDS dest = wave-uniform base + lane*16) ----
  // A window wnd (64 K-cols): 8KB, 1 gload/thread. slot s holds chunk s^(row&7).
  auto stageA = [&](int wnd) {
    char* abuf = lds + ((wnd & 1) ? 8192 : 0);
    int row = tid >> 3, slin = tid & 7;
    const unsigned short* src = wnd < 2 ? hbf : (wnd < 4 ? xbf : aggbf);
    int woff = (wnd & 1) * 128;
    gload16((const char*)src + (size_t)(m0 + row) * 256 + woff + ((slin ^ (row & 7)) * 16),
            abuf + tid * 16);
  };
  // B step ks (32 K-cols x 512 rows): 32KB, 4 gloads/thread. slot s holds chunk s^((row>>1)&3).
  auto stageB = [&](int ks) {
    char* bbuf = lds + ((ks & 1) ? 49152 : 16384);
#pragma unroll
    for (int q = 0; q < 4; ++q) {
      int sabs = q * 512 + tid;
      int row = sabs >> 2, slin = sabs & 3;
      gload16((const char*)Ut + (size_t)row * 768 + ks * 64 + ((slin ^ ((row >> 1) & 3)) * 16),
              bbuf + q * 8192 + tid * 16);
    }
  };

  // ---- prologue: issue B0, A0, B1, A1 (10 loads in flight) ----
  stageB(0);
  stageA(0);
  stageB(1);
  stageA(1);

  // ---- fused neighbor-mean gather for this block's 64 rows ----
  {
    int r0 = m0 + w * 8;
    int pre = r0 + (lane & 7);
    int rsv = 0, dgv = 0;
    if (pre < nrows) {
      if (lane < 8) rsv = row_start[pre];
      else if (lane < 16) dgv = counts[pre];
    }
    int g4 = lane >> 4, t16 = lane & 15;
#pragma unroll
    for (int b = 0; b < 2; ++b) {
      float a0[8] = {}, a1[8] = {}, a2[8] = {}, a3[8] = {};
      int s0 = __shfl(rsv, b * 4 + 0), d0 = __shfl(dgv, 8 + b * 4 + 0);
      int s1 = __shfl(rsv, b * 4 + 1), d1 = __shfl(dgv, 8 + b * 4 + 1);
      int s2 = __shfl(rsv, b * 4 + 2), d2 = __shfl(dgv, 8 + b * 4 + 2);
      int s3 = __shfl(rsv, b * 4 + 3), d3 = __shfl(dgv, 8 + b * 4 + 3);
      int dm = d0 > d1 ? d0 : d1;
      dm = d2 > dm ? d2 : dm;
      dm = d3 > dm ? d3 : dm;
      for (int i = 0; i < dm; i += 4) {
        int idx = i + g4;
        bf16x8 v0, v1, v2, v3;
        bool c0 = idx < d0, c1 = idx < d1, c2 = idx < d2, c3 = idx < d3;
        if (c0) { int sv = csr[s0 + idx]; v0 = *(const bf16x8*)(hbf + (size_t)sv * DD + t16 * 8); }
        if (c1) { int sv = csr[s1 + idx]; v1 = *(const bf16x8*)(hbf + (size_t)sv * DD + t16 * 8); }
        if (c2) { int sv = csr[s2 + idx]; v2 = *(const bf16x8*)(hbf + (size_t)sv * DD + t16 * 8); }
        if (c3) { int sv = csr[s3 + idx]; v3 = *(const bf16x8*)(hbf + (size_t)sv * DD + t16 * 8); }
#pragma unroll
        for (int q = 0; q < 8; ++q) {
          if (c0) a0[q] += bf2f((unsigned short)v0[q]);
          if (c1) a1[q] += bf2f((unsigned short)v1[q]);
          if (c2) a2[q] += bf2f((unsigned short)v2[q]);
          if (c3) a3[q] += bf2f((unsigned short)v3[q]);
        }
      }
#pragma unroll
      for (int q = 0; q < 8; ++q) {
        a0[q] += __shfl_xor(a0[q], 16); a0[q] += __shfl_xor(a0[q], 32);
        a1[q] += __shfl_xor(a1[q], 16); a1[q] += __shfl_xor(a1[q], 32);
        a2[q] += __shfl_xor(a2[q], 16); a2[q] += __shfl_xor(a2[q], 32);
        a3[q] += __shfl_xor(a3[q], 16); a3[q] += __shfl_xor(a3[q], 32);
      }
      if (lane < 16) {
        float i0 = 1.f / fmaxf((float)d0, 1.f);
        float i1 = 1.f / fmaxf((float)d1, 1.f);
        float i2 = 1.f / fmaxf((float)d2, 1.f);
        float i3 = 1.f / fmaxf((float)d3, 1.f);
        bf16x8 o0, o1, o2, o3;
#pragma unroll
        for (int q = 0; q < 8; ++q) {
          o0[q] = (short)f2bf(a0[q] * i0);
          o1[q] = (short)f2bf(a1[q] * i1);
          o2[q] = (short)f2bf(a2[q] * i2);
          o3[q] = (short)f2bf(a3[q] * i3);
        }
        int rb = r0 + b * 4;
        if (rb + 0 < nrows) *(bf16x8*)(aggbf + (size_t)(rb + 0) * DD + lane * 8) = o0;
        if (rb + 1 < nrows) *(bf16x8*)(aggbf + (size_t)(rb + 1) * DD + lane * 8) = o1;
        if (rb + 2 < nrows) *(bf16x8*)(aggbf + (size_t)(rb + 2) * DD + lane * 8) = o2;
        if (rb + 3 < nrows) *(bf16x8*)(aggbf + (size_t)(rb + 3) * DD + lane * 8) = o3;
      }
    }
  }
  // agg stores + all prologue staging complete; visible block-wide
  asm volatile("s_waitcnt vmcnt(0)" ::: "memory");
  __builtin_amdgcn_sched_barrier(0);
  __builtin_amdgcn_s_barrier();

  f32x4 acc[4][4];
#pragma unroll
  for (int mi = 0; mi < 4; ++mi)
#pragma unroll
    for (int ni = 0; ni < 4; ++ni) acc[mi][ni] = (f32x4){0.f, 0.f, 0.f, 0.f};

  // ---- 12-step K loop: A window = ks>>1, parity selects 32-col half ----
#pragma unroll
  for (int ks = 0; ks < 12; ++ks) {
    const char* As = lds + (((ks >> 1) & 1) ? 8192 : 0);
    const char* Bs = lds + ((ks & 1) ? 49152 : 16384);
    const int p = ks & 1;
    bf16x8 af[4], bq[4];
#pragma unroll
    for (int mi = 0; mi < 4; ++mi) {
      int r = mi * 16 + l15;
      af[mi] = *(const bf16x8*)(As + r * 128 + (((p * 4 + rg) ^ (r & 7)) * 16));
    }
#pragma unroll
    for (int ni = 0; ni < 4; ++ni) {
      int r = w * 64 + ni * 16 + l15;
      bq[ni] = *(const bf16x8*)(Bs + r * 64 + ((rg ^ ((r >> 1) & 3)) * 16));
    }
    asm volatile("s_waitcnt lgkmcnt(0)" ::: "memory");
    __builtin_amdgcn_sched_barrier(0);
    __builtin_amdgcn_s_barrier();
    // restage: B(ks+2) always (ks<10); A window (ks+3)>>1 at odd ks<=7
    if (ks < 10) stageB(ks + 2);
    if ((ks & 1) && ks <= 7) stageA((ks + 3) >> 1);
    __builtin_amdgcn_s_setprio(1);
#pragma unroll
    for (int mi = 0; mi < 4; ++mi)
#pragma unroll
      for (int ni = 0; ni < 4; ++ni)
        acc[mi][ni] = __builtin_amdgcn_mfma_f32_16x16x32_bf16(af[mi], bq[ni], acc[mi][ni], 0, 0, 0);
    __builtin_amdgcn_s_setprio(0);
    if (ks <= 8) {
      asm volatile("s_waitcnt vmcnt(5)" ::: "memory");
    } else if (ks == 9) {
      asm volatile("s_waitcnt vmcnt(4)" ::: "memory");
    } else if (ks == 10) {
      asm volatile("s_waitcnt vmcnt(0)" ::: "memory");
    }
    __builtin_amdgcn_sched_barrier(0);
    __builtin_amdgcn_s_barrier();
  }

  // ---- epilogue: stage gates (64 x 512 bf16, XOR-swizzled) into LDS[0,64K) ----
  float bias_v[4];
#pragma unroll
  for (int ni = 0; ni < 4; ++ni) bias_v[ni] = bias[w * 64 + ni * 16 + l15];
#pragma unroll
  for (int mi = 0; mi < 4; ++mi)
#pragma unroll
    for (int ni = 0; ni < 4; ++ni) {
      int col = w * 64 + ni * 16 + l15;
#pragma unroll
      for (int j = 0; j < 4; ++j) {
        int row = mi * 16 + rg * 4 + j;
        int byte = (row * 1024 + col * 2) ^ ((row & 7) << 4);
        *(unsigned short*)(lds + byte) = f2bf(acc[mi][ni][j] + bias_v[ni]);
      }
    }
  asm volatile("s_waitcnt lgkmcnt(0)" ::: "memory");
  __builtin_amdgcn_sched_barrier(0);
  __builtin_amdgcn_s_barrier();

#pragma unroll 1
  for (int t = 0; t < 8; ++t) {
    int rr = w * 8 + t;
    int rowg = m0 + rr;
    if (rowg >= nrows) continue;  // wave-uniform
    int c = lane * 2;
    int sw = (rr & 7) << 4;
    ushort2 fu = *(const ushort2*)(lds + ((rr * 1024 + 0 + lane * 4) ^ sw));
    ushort2 iu = *(const ushort2*)(lds + ((rr * 1024 + 256 + lane * 4) ^ sw));
    ushort2 cu = *(const ushort2*)(lds + ((rr * 1024 + 512 + lane * 4) ^ sw));
    ushort2 ou = *(const ushort2*)(lds + ((rr * 1024 + 768 + lane * 4) ^ sw));
    float2 cv = *(const float2*)(cell + (size_t)rowg * DD + c);
    float f0 = fsigmoid(bf2f(fu.x)), f1 = fsigmoid(bf2f(fu.y));
    float i0 = fsigmoid(bf2f(iu.x)), i1 = fsigmoid(bf2f(iu.y));
    float t0 = ftanh(bf2f(cu.x)), t1 = ftanh(bf2f(cu.y));
    float o0 = fsigmoid(bf2f(ou.x)), o1 = fsigmoid(bf2f(ou.y));
    float cn0 = f0 * cv.x + i0 * t0;
    float cn1 = f1 * cv.y + i1 * t1;
    float y0 = o0 * ftanh(cn0);
    float y1 = o1 * ftanh(cn1);
    float s = y0 + y1, s2 = y0 * y0 + y1 * y1;
#pragma unroll
    for (int off = 1; off < 64; off <<= 1) {
      s += __shfl_xor(s, off);
      s2 += __shfl_xor(s2, off);
    }
    float mean = s * (1.f / 128.f);
    float var = s2 * (1.f / 128.f) - mean * mean;
    float rstd = rsqrtf(var + 1e-5f);
    float2 gm = *(const float2*)(gamma + c);
    float2 bt = *(const float2*)(beta + c);
    float h0 = (y0 - mean) * rstd * gm.x + bt.x;
    float h1 = (y1 - mean) * rstd * gm.y + bt.y;
    *(float2*)(out + (size_t)rowg * DD + c) = make_float2(h0, h1);
    *(float2*)(out + (size_t)nrows * DD + (size_t)rowg * DD + c) = make_float2(cn0, cn1);
  }
}

extern "C" void kernel_launch(void* const* d_in, const int* in_sizes, int n_in,
                              void* d_out, int out_size, void* d_ws, size_t ws_size,
                              hipStream_t stream) {
  const float* h = (const float*)d_in[0];
  const float* cellp = (const float*)d_in[1];
  const float* x = (const float*)d_in[2];
  const int* edge = (const int*)d_in[3];
  const float* Wg0 = (const float*)d_in[4];
  const float* bg0 = (const float*)d_in[5];
  const float* Wg1 = (const float*)d_in[6];
  const float* bg1 = (const float*)d_in[7];
  const float* Wg2 = (const float*)d_in[8];
  const float* bg2 = (const float*)d_in[9];
  const float* Wg3 = (const float*)d_in[10];
  const float* bg3 = (const float*)d_in[11];
  const float* Wl0 = (const float*)d_in[12];
  const float* bl0 = (const float*)d_in[13];
  const float* Wr0 = (const float*)d_in[14];
  const float* Wl1 = (const float*)d_in[15];
  const float* bl1 = (const float*)d_in[16];
  const float* Wr1 = (const float*)d_in[17];
  const float* Wl2 = (const float*)d_in[18];
  const float* bl2 = (const float*)d_in[19];
  const float* Wr2 = (const float*)d_in[20];
  const float* Wl3 = (const float*)d_in[21];
  const float* bl3 = (const float*)d_in[22];
  const float* Wr3 = (const float*)d_in[23];
  const float* gamma = (const float*)d_in[24];
  const float* beta = (const float*)d_in[25];

  int N = in_sizes[0] / DD;
  int E = in_sizes[3] / 2;
  int Mpad = ((N + 63) / 64) * 64;

  char* ws = (char*)d_ws;
  size_t off = 0;
  auto alloc = [&](size_t b) {
    char* p = ws + off;
    off += (b + 255) & ~(size_t)255;
    return p;
  };
  int* counts = (int*)alloc((size_t)N * 4);
  int* cursor = (int*)alloc((size_t)N * 4);
  int* row_start = (int*)alloc((size_t)N * 4);
  int* gcur = (int*)alloc(4);
  int* csr = (int*)alloc((size_t)E * 4);
  unsigned short* hbf = (unsigned short*)alloc((size_t)Mpad * DD * 2);
  unsigned short* xbf = (unsigned short*)alloc((size_t)Mpad * DD * 2);
  unsigned short* aggbf = (unsigned short*)alloc((size_t)Mpad * DD * 2);
  unsigned short* Ut = (unsigned short*)alloc((size_t)NG * KK * 2);
  float* bias = (float*)alloc((size_t)NG * 4);
  (void)ws_size;
  (void)n_in;
  (void)out_size;

  const int* esrc = edge;
  const int* edst = edge + E;

  int conv_items = Mpad * DD / 4;
  long init_total = (long)conv_items + NG * KK + 2L * N + 1;
  int init_blocks = (int)((init_total + 255) / 256);

  k_init<<<init_blocks, 256, 0, stream>>>(
      h, x, hbf, xbf,
      Wg0, Wg1, Wg2, Wg3, Wl0, Wl1, Wl2, Wl3, Wr0, Wr1, Wr2, Wr3,
      bg0, bg1, bg2, bg3, bl0, bl1, bl2, bl3, Ut, bias,
      counts, cursor, gcur, N, N * DD, conv_items);
  k_count<<<(E + 255) / 256, 256, 0, stream>>>(edst, counts, E);
  k_partition<<<(N + 255) / 256, 256, 0, stream>>>(counts, row_start, gcur, N);
  k_scatter<<<(E + 255) / 256, 256, 0, stream>>>(esrc, edst, row_start, cursor, csr, E);
  k_gemm_fused<<<Mpad / 64, 512, 0, stream>>>(hbf, xbf, aggbf, Ut,
                                              row_start, counts, csr,
                                              bias, cellp, gamma, beta,
                                              (float*)d_out, N);
}

// Round 8
// 208.728 us; speedup vs baseline: 1.0135x; 1.0135x over previous
//
#include <hip/hip_runtime.h>

#define DD 128
#define KK 384
#define NG 512

typedef __attribute__((ext_vector_type(8))) short bf16x8;
typedef __attribute__((ext_vector_type(4))) float f32x4;

__device__ __forceinline__ float bf2f(unsigned short u) {
  return __uint_as_float(((unsigned int)u) << 16);
}
__device__ __forceinline__ unsigned short f2bf(float f) {
  unsigned int x = __float_as_uint(f);
  x += 0x7fffu + ((x >> 16) & 1u);
  return (unsigned short)(x >> 16);
}
__device__ __forceinline__ float fsigmoid(float v) {
  return 1.f / (1.f + __expf(-v));
}
__device__ __forceinline__ float ftanh(float v) {
  float t = __expf(2.f * v);
  return (t - 1.f) / (t + 1.f);
}

// f32->bf16 convert of h,x (zero-padded to Mpad) + fused-weight build.
__global__ void k_init(const float* __restrict__ h, const float* __restrict__ x,
                       unsigned short* __restrict__ hbf, unsigned short* __restrict__ xbf,
                       const float* __restrict__ Wg0, const float* __restrict__ Wg1,
                       const float* __restrict__ Wg2, const float* __restrict__ Wg3,
                       const float* __restrict__ Wl0, const float* __restrict__ Wl1,
                       const float* __restrict__ Wl2, const float* __restrict__ Wl3,
                       const float* __restrict__ Wr0, const float* __restrict__ Wr1,
                       const float* __restrict__ Wr2, const float* __restrict__ Wr3,
                       const float* __restrict__ bg0, const float* __restrict__ bg1,
                       const float* __restrict__ bg2, const float* __restrict__ bg3,
                       const float* __restrict__ bl0, const float* __restrict__ bl1,
                       const float* __restrict__ bl2, const float* __restrict__ bl3,
                       unsigned short* __restrict__ Ut, float* __restrict__ bias,
                       int n128, int conv_items) {
  long gid = (long)blockIdx.x * blockDim.x + threadIdx.x;
  if (gid < conv_items) {
    int i = (int)gid * 4;
    ushort4 ho, xo;
    if (i < n128) {
      float4 hv = *(const float4*)(h + i);
      float4 xv = *(const float4*)(x + i);
      ho = make_ushort4(f2bf(hv.x), f2bf(hv.y), f2bf(hv.z), f2bf(hv.w));
      xo = make_ushort4(f2bf(xv.x), f2bf(xv.y), f2bf(xv.z), f2bf(xv.w));
    } else {
      ho = make_ushort4(0, 0, 0, 0);
      xo = make_ushort4(0, 0, 0, 0);
    }
    *(ushort4*)(hbf + i) = ho;
    *(ushort4*)(xbf + i) = xo;
    return;
  }
  gid -= conv_items;
  if (gid < NG * KK) {
    int id = (int)gid;
    int nn = id / KK, k = id % KK;
    int g = nn >> 7, c = nn & 127;
    const float* Wg = g == 0 ? Wg0 : g == 1 ? Wg1 : g == 2 ? Wg2 : Wg3;
    const float* Wl = g == 0 ? Wl0 : g == 1 ? Wl1 : g == 2 ? Wl2 : Wl3;
    const float* Wr = g == 0 ? Wr0 : g == 1 ? Wr1 : g == 2 ? Wr2 : Wr3;
    float v;
    if (k < 128)      v = Wg[k * DD + c] + Wr[k * DD + c];
    else if (k < 256) v = Wg[k * DD + c];
    else              v = Wl[(k - 256) * DD + c];
    Ut[(size_t)nn * KK + k] = f2bf(v);
    if (k == 0) {
      const float* bgp = g == 0 ? bg0 : g == 1 ? bg1 : g == 2 ? bg2 : bg3;
      const float* blp = g == 0 ? bl0 : g == 1 ? bl1 : g == 2 ? bl2 : bl3;
      bias[nn] = bgp[c] + blp[c];
    }
  }
}

__global__ void k_count(const int* __restrict__ dst, int* __restrict__ counts, int E) {
  int e = blockIdx.x * blockDim.x + threadIdx.x;
  if (e < E) atomicAdd(counts + dst[e], 1);
}

__global__ void k_partition(const int* __restrict__ counts, int* __restrict__ row_start,
                            int* __restrict__ gcur, int n) {
  int i = blockIdx.x * blockDim.x + threadIdx.x;
  int lane = threadIdx.x & 63;
  int v = (i < n) ? counts[i] : 0;
  int s = v;
#pragma unroll
  for (int off = 1; off < 64; off <<= 1) {
    int t = __shfl_up(s, off);
    if (lane >= off) s += t;
  }
  int total = __shfl(s, 63);
  int base = 0;
  if (lane == 63) base = atomicAdd(gcur, total);
  base = __shfl(base, 63);
  if (i < n) row_start[i] = base + s - v;
}

__global__ void k_scatter(const int* __restrict__ srcv, const int* __restrict__ dstv,
                          const int* __restrict__ row_start, int* __restrict__ cursor,
                          int* __restrict__ csr, int E) {
  int e = blockIdx.x * blockDim.x + threadIdx.x;
  if (e < E) {
    int d = dstv[e];
    int pos = row_start[d] + atomicAdd(cursor + d, 1);
    csr[pos] = srcv[e];
  }
}

// One wave per node. 4 neighbor-groups x 16 lanes x bf16x8(16B) per row.
// Unconditional clamped loads (no exec-mask serialization) + 1-deep csr
// index prefetch: next iteration's index load issues while this iteration's
// row load is in flight.
__global__ void k_agg(const unsigned short* __restrict__ hbf, const int* __restrict__ row_start,
                      const int* __restrict__ counts, const int* __restrict__ csr,
                      unsigned short* __restrict__ aggbf, int n, int mpad) {
  int wave = (blockIdx.x * blockDim.x + threadIdx.x) >> 6;
  int lane = threadIdx.x & 63;
  if (wave >= mpad) return;
  int g = lane >> 4;
  int t = lane & 15;
  float acc[8] = {0.f, 0.f, 0.f, 0.f, 0.f, 0.f, 0.f, 0.f};
  if (wave < n) {
    int s = row_start[wave], deg = counts[wave];
    if (deg > 0) {
      int e = s + deg;
      int last = e - 1;
      int jj = s + g;
      int jc = jj < last ? jj : last;
      int src = csr[jc];
      int iters = (deg + 3) >> 2;
      for (int it = 0; it < iters; ++it) {
        int jjn = jj + 4;
        int jcn = jjn < last ? jjn : last;
        int srcn = csr[jcn];  // prefetch next index (clamped, always safe)
        bf16x8 v = *(const bf16x8*)(hbf + (size_t)src * DD + t * 8);
        float m = jj < e ? 1.f : 0.f;
#pragma unroll
        for (int q = 0; q < 8; ++q) acc[q] += m * bf2f((unsigned short)v[q]);
        src = srcn;
        jj = jjn;
      }
      float inv = 1.f / (float)deg;
#pragma unroll
      for (int q = 0; q < 8; ++q) {
        acc[q] += __shfl_xor(acc[q], 16);
        acc[q] += __shfl_xor(acc[q], 32);
        acc[q] *= inv;
      }
    }
  }
  if (g == 0) {
    bf16x8 o;
#pragma unroll
    for (int q = 0; q < 8; ++q) o[q] = (short)f2bf(acc[q]);
    *(bf16x8*)(aggbf + (size_t)wave * DD + t * 8) = o;
  }
}

__device__ __forceinline__ void gload16(const void* g, void* l) {
  __builtin_amdgcn_global_load_lds((__attribute__((address_space(1))) void*)(void*)g,
                                   (__attribute__((address_space(3))) void*)l, 16, 0, 0);
}

// Fused GEMM + LSTM-gate + LayerNorm (round-4 verified config).
// BM=128, BN=512, BK=64; 1024 threads = 16 waves (2Mx8N), wave tile 64x64.
// LDS: A 16KB single + B 2x64KB double-buffered = 144KB (1 block/CU).
// Counted-vmcnt pipeline: loads stay in flight across raw s_barriers.
#define ABUF 0
#define BBUF0 16384
#define BBUF1 81920
__global__ __launch_bounds__(1024, 4) void k_gemm_fused(
    const unsigned short* __restrict__ hbf, const unsigned short* __restrict__ xbf,
    const unsigned short* __restrict__ aggbf, const unsigned short* __restrict__ Ut,
    const float* __restrict__ bias, const float* __restrict__ cell,
    const float* __restrict__ gamma, const float* __restrict__ beta,
    float* __restrict__ out, int nrows) {
  __shared__ char lds[147456];  // 144KB; epilogue reuses first 128KB
  const int m0 = blockIdx.x * 128;
  const int tid = threadIdx.x;
  const int w = tid >> 6, lane = tid & 63;
  const int wr = w >> 3, wc = w & 7;
  const int l15 = lane & 15, rg = lane >> 4;
  f32x4 acc[4][4] = {};

  const int srow = tid >> 3;   // 0..127 staging row
  const int sslot = tid & 7;   // 16B slot in 128B row

  auto stageA = [&](int ks) {
    const unsigned short* Ab = ks < 2 ? hbf : (ks < 4 ? xbf : aggbf);
    const int akoff = (ks & 1) * 128;
    int d = sslot ^ (srow & 7);
    gload16((const char*)Ab + (size_t)(m0 + srow) * 256 + akoff + d * 16,
            lds + ABUF + tid * 16);
  };
  auto stageB = [&](int ks, int bbase) {
    const int bkoff = ks * 128;
#pragma unroll
    for (int p = 0; p < 4; ++p) {
      int r = p * 128 + srow;
      int d = sslot ^ (r & 7);
      gload16((const char*)Ut + (size_t)r * 768 + bkoff + d * 16,
              lds + bbase + p * 16384 + tid * 16);
    }
  };

  // prologue: B(0), A(0), B(1) in flight; wait for B(0)+A(0)
  stageB(0, BBUF0);
  stageA(0);
  stageB(1, BBUF1);
  asm volatile("s_waitcnt vmcnt(4)" ::: "memory");
  __builtin_amdgcn_sched_barrier(0);
  __builtin_amdgcn_s_barrier();

#pragma unroll
  for (int ks = 0; ks < 6; ++ks) {
    const char* As = lds + ABUF;
    const char* Bs = lds + (ks & 1 ? BBUF1 : BBUF0);
    // ---- slice 0 ----
    bf16x8 af0[4], bq0[4];
#pragma unroll
    for (int mi = 0; mi < 4; ++mi) {
      int r = wr * 64 + mi * 16 + l15;
      af0[mi] = *(const bf16x8*)(As + r * 128 + ((rg ^ (r & 7)) * 16));
    }
#pragma unroll
    for (int ni = 0; ni < 4; ++ni) {
      int r = wc * 64 + ni * 16 + l15;
      bq0[ni] = *(const bf16x8*)(Bs + r * 128 + ((rg ^ (r & 7)) * 16));
    }
#pragma unroll
    for (int mi = 0; mi < 4; ++mi)
#pragma unroll
      for (int ni = 0; ni < 4; ++ni)
        acc[mi][ni] = __builtin_amdgcn_mfma_f32_16x16x32_bf16(af0[mi], bq0[ni], acc[mi][ni], 0, 0, 0);
    // ---- slice 1 ----
    bf16x8 af1[4], bq1[4];
#pragma unroll
    for (int mi = 0; mi < 4; ++mi) {
      int r = wr * 64 + mi * 16 + l15;
      af1[mi] = *(const bf16x8*)(As + r * 128 + (((4 + rg) ^ (r & 7)) * 16));
    }
#pragma unroll
    for (int ni = 0; ni < 4; ++ni) {
      int r = wc * 64 + ni * 16 + l15;
      bq1[ni] = *(const bf16x8*)(Bs + r * 128 + (((4 + rg) ^ (r & 7)) * 16));
    }
    // all LDS reads of this step done before anyone restages these buffers
    asm volatile("s_waitcnt lgkmcnt(0)" ::: "memory");
    __builtin_amdgcn_sched_barrier(0);
    __builtin_amdgcn_s_barrier();
    if (ks < 5) stageA(ks + 1);
    if (ks < 4) stageB(ks + 2, (ks & 1) ? BBUF1 : BBUF0);
#pragma unroll
    for (int mi = 0; mi < 4; ++mi)
#pragma unroll
      for (int ni = 0; ni < 4; ++ni)
        acc[mi][ni] = __builtin_amdgcn_mfma_f32_16x16x32_bf16(af1[mi], bq1[ni], acc[mi][ni], 0, 0, 0);
    if (ks < 4) {
      asm volatile("s_waitcnt vmcnt(4)" ::: "memory");  // A(k+1)+B(k+1) landed
    } else if (ks == 4) {
      asm volatile("s_waitcnt vmcnt(0)" ::: "memory");
    }
    __builtin_amdgcn_sched_barrier(0);
    __builtin_amdgcn_s_barrier();
  }

  // stage gates (128 rows x 512 cols bf16, XOR-swizzled) into LDS[0..128KB)
  float bias_v[4];
#pragma unroll
  for (int ni = 0; ni < 4; ++ni) bias_v[ni] = bias[wc * 64 + ni * 16 + l15];
#pragma unroll
  for (int mi = 0; mi < 4; ++mi)
#pragma unroll
    for (int ni = 0; ni < 4; ++ni) {
      int col = wc * 64 + ni * 16 + l15;
#pragma unroll
      for (int j = 0; j < 4; ++j) {
        int row = wr * 64 + mi * 16 + rg * 4 + j;
        int byte = (row * 1024 + col * 2) ^ ((row & 7) << 4);
        *(unsigned short*)(lds + byte) = f2bf(acc[mi][ni][j] + bias_v[ni]);
      }
    }
  asm volatile("s_waitcnt lgkmcnt(0)" ::: "memory");
  __builtin_amdgcn_sched_barrier(0);
  __builtin_amdgcn_s_barrier();

#pragma unroll 1
  for (int t = 0; t < 8; ++t) {
    int rr = w * 8 + t;
    int rowg = m0 + rr;
    if (rowg >= nrows) continue;  // wave-uniform
    int c = lane * 2;
    int sw = (rr & 7) << 4;
    ushort2 fu = *(const ushort2*)(lds + ((rr * 1024 + 0 + lane * 4) ^ sw));
    ushort2 iu = *(const ushort2*)(lds + ((rr * 1024 + 256 + lane * 4) ^ sw));
    ushort2 cu = *(const ushort2*)(lds + ((rr * 1024 + 512 + lane * 4) ^ sw));
    ushort2 ou = *(const ushort2*)(lds + ((rr * 1024 + 768 + lane * 4) ^ sw));
    float2 cv = *(const float2*)(cell + (size_t)rowg * DD + c);
    float f0 = fsigmoid(bf2f(fu.x)), f1 = fsigmoid(bf2f(fu.y));
    float i0 = fsigmoid(bf2f(iu.x)), i1 = fsigmoid(bf2f(iu.y));
    float t0 = ftanh(bf2f(cu.x)), t1 = ftanh(bf2f(cu.y));
    float o0 = fsigmoid(bf2f(ou.x)), o1 = fsigmoid(bf2f(ou.y));
    float cn0 = f0 * cv.x + i0 * t0;
    float cn1 = f1 * cv.y + i1 * t1;
    float y0 = o0 * ftanh(cn0);
    float y1 = o1 * ftanh(cn1);
    float s = y0 + y1, s2 = y0 * y0 + y1 * y1;
#pragma unroll
    for (int off = 1; off < 64; off <<= 1) {
      s += __shfl_xor(s, off);
      s2 += __shfl_xor(s2, off);
    }
    float mean = s * (1.f / 128.f);
    float var = s2 * (1.f / 128.f) - mean * mean;
    float rstd = rsqrtf(var + 1e-5f);
    float2 gm = *(const float2*)(gamma + c);
    float2 bt = *(const float2*)(beta + c);
    float h0 = (y0 - mean) * rstd * gm.x + bt.x;
    float h1 = (y1 - mean) * rstd * gm.y + bt.y;
    *(float2*)(out + (size_t)rowg * DD + c) = make_float2(h0, h1);
    *(float2*)(out + (size_t)nrows * DD + (size_t)rowg * DD + c) = make_float2(cn0, cn1);
  }
}

extern "C" void kernel_launch(void* const* d_in, const int* in_sizes, int n_in,
                              void* d_out, int out_size, void* d_ws, size_t ws_size,
                              hipStream_t stream) {
  const float* h = (const float*)d_in[0];
  const float* cellp = (const float*)d_in[1];
  const float* x = (const float*)d_in[2];
  const int* edge = (const int*)d_in[3];
  const float* Wg0 = (const float*)d_in[4];
  const float* bg0 = (const float*)d_in[5];
  const float* Wg1 = (const float*)d_in[6];
  const float* bg1 = (const float*)d_in[7];
  const float* Wg2 = (const float*)d_in[8];
  const float* bg2 = (const float*)d_in[9];
  const float* Wg3 = (const float*)d_in[10];
  const float* bg3 = (const float*)d_in[11];
  const float* Wl0 = (const float*)d_in[12];
  const float* bl0 = (const float*)d_in[13];
  const float* Wr0 = (const float*)d_in[14];
  const float* Wl1 = (const float*)d_in[15];
  const float* bl1 = (const float*)d_in[16];
  const float* Wr1 = (const float*)d_in[17];
  const float* Wl2 = (const float*)d_in[18];
  const float* bl2 = (const float*)d_in[19];
  const float* Wr2 = (const float*)d_in[20];
  const float* Wl3 = (const float*)d_in[21];
  const float* bl3 = (const float*)d_in[22];
  const float* Wr3 = (const float*)d_in[23];
  const float* gamma = (const float*)d_in[24];
  const float* beta = (const float*)d_in[25];

  int N = in_sizes[0] / DD;
  int E = in_sizes[3] / 2;
  int Mpad = ((N + 127) / 128) * 128;

  char* ws = (char*)d_ws;
  size_t off = 0;
  auto alloc = [&](size_t b) {
    char* p = ws + off;
    off += (b + 255) & ~(size_t)255;
    return p;
  };
  int* counts = (int*)alloc((size_t)N * 4);
  int* cursor = (int*)alloc((size_t)N * 4);
  int* row_start = (int*)alloc((size_t)N * 4);
  int* gcur = (int*)alloc(4);
  size_t zero_span = (size_t)((char*)gcur - (char*)counts) + 4;
  int* csr = (int*)alloc((size_t)E * 4);
  unsigned short* hbf = (unsigned short*)alloc((size_t)Mpad * DD * 2);
  unsigned short* xbf = (unsigned short*)alloc((size_t)Mpad * DD * 2);
  unsigned short* aggbf = (unsigned short*)alloc((size_t)Mpad * DD * 2);
  unsigned short* Ut = (unsigned short*)alloc((size_t)NG * KK * 2);
  float* bias = (float*)alloc((size_t)NG * 4);
  (void)ws_size;
  (void)n_in;
  (void)out_size;

  const int* esrc = edge;
  const int* edst = edge + E;

  int conv_items = Mpad * DD / 4;
  long init_total = (long)conv_items + NG * KK;
  int init_blocks = (int)((init_total + 255) / 256);

  hipMemsetAsync(counts, 0, zero_span, stream);
  k_count<<<(E + 255) / 256, 256, 0, stream>>>(edst, counts, E);
  k_init<<<init_blocks, 256, 0, stream>>>(
      h, x, hbf, xbf,
      Wg0, Wg1, Wg2, Wg3, Wl0, Wl1, Wl2, Wl3, Wr0, Wr1, Wr2, Wr3,
      bg0, bg1, bg2, bg3, bl0, bl1, bl2, bl3, Ut, bias,
      N * DD, conv_items);
  k_partition<<<(N + 255) / 256, 256, 0, stream>>>(counts, row_start, gcur, N);
  k_scatter<<<(E + 255) / 256, 256, 0, stream>>>(esrc, edst, row_start, cursor, csr, E);
  k_agg<<<Mpad / 4, 256, 0, stream>>>(hbf, row_start, counts, csr, aggbf, N, Mpad);
  k_gemm_fused<<<Mpad / 128, 1024, 0, stream>>>(hbf, xbf, aggbf, Ut, bias, cellp,
                                                gamma, beta, (float*)d_out, N);
}

// Round 9
// 196.406 us; speedup vs baseline: 1.0771x; 1.0627x over previous
//
#include <hip/hip_runtime.h>

#define DD 128
#define KK 384
#define NG 512

typedef __attribute__((ext_vector_type(8))) short bf16x8;
typedef __attribute__((ext_vector_type(4))) float f32x4;

__device__ __forceinline__ float bf2f(unsigned short u) {
  return __uint_as_float(((unsigned int)u) << 16);
}
__device__ __forceinline__ unsigned short f2bf(float f) {
  unsigned int x = __float_as_uint(f);
  x += 0x7fffu + ((x >> 16) & 1u);
  return (unsigned short)(x >> 16);
}
__device__ __forceinline__ float fsigmoid(float v) {
  return 1.f / (1.f + __expf(-v));
}
__device__ __forceinline__ float ftanh(float v) {
  float t = __expf(2.f * v);
  return (t - 1.f) / (t + 1.f);
}

// f32->bf16 convert of h,x + fused-weight build + edge-count atomics (independent
// work fused into one launch; counts must be zeroed before this kernel).
__global__ void k_init(const float* __restrict__ h, const float* __restrict__ x,
                       unsigned short* __restrict__ hbf, unsigned short* __restrict__ xbf,
                       const float* __restrict__ Wg0, const float* __restrict__ Wg1,
                       const float* __restrict__ Wg2, const float* __restrict__ Wg3,
                       const float* __restrict__ Wl0, const float* __restrict__ Wl1,
                       const float* __restrict__ Wl2, const float* __restrict__ Wl3,
                       const float* __restrict__ Wr0, const float* __restrict__ Wr1,
                       const float* __restrict__ Wr2, const float* __restrict__ Wr3,
                       const float* __restrict__ bg0, const float* __restrict__ bg1,
                       const float* __restrict__ bg2, const float* __restrict__ bg3,
                       const float* __restrict__ bl0, const float* __restrict__ bl1,
                       const float* __restrict__ bl2, const float* __restrict__ bl3,
                       unsigned short* __restrict__ Ut, float* __restrict__ bias,
                       const int* __restrict__ edst, int* __restrict__ counts,
                       int E, int n128, int conv_items) {
  long gid = (long)blockIdx.x * blockDim.x + threadIdx.x;
  if (gid < conv_items) {
    int i = (int)gid * 4;
    ushort4 ho, xo;
    if (i < n128) {
      float4 hv = *(const float4*)(h + i);
      float4 xv = *(const float4*)(x + i);
      ho = make_ushort4(f2bf(hv.x), f2bf(hv.y), f2bf(hv.z), f2bf(hv.w));
      xo = make_ushort4(f2bf(xv.x), f2bf(xv.y), f2bf(xv.z), f2bf(xv.w));
    } else {
      ho = make_ushort4(0, 0, 0, 0);
      xo = make_ushort4(0, 0, 0, 0);
    }
    *(ushort4*)(hbf + i) = ho;
    *(ushort4*)(xbf + i) = xo;
    return;
  }
  gid -= conv_items;
  if (gid < NG * KK) {
    int id = (int)gid;
    int nn = id / KK, k = id % KK;
    int g = nn >> 7, c = nn & 127;
    const float* Wg = g == 0 ? Wg0 : g == 1 ? Wg1 : g == 2 ? Wg2 : Wg3;
    const float* Wl = g == 0 ? Wl0 : g == 1 ? Wl1 : g == 2 ? Wl2 : Wl3;
    const float* Wr = g == 0 ? Wr0 : g == 1 ? Wr1 : g == 2 ? Wr2 : Wr3;
    float v;
    if (k < 128)      v = Wg[k * DD + c] + Wr[k * DD + c];
    else if (k < 256) v = Wg[k * DD + c];
    else              v = Wl[(k - 256) * DD + c];
    Ut[(size_t)nn * KK + k] = f2bf(v);
    if (k == 0) {
      const float* bgp = g == 0 ? bg0 : g == 1 ? bg1 : g == 2 ? bg2 : bg3;
      const float* blp = g == 0 ? bl0 : g == 1 ? bl1 : g == 2 ? bl2 : bl3;
      bias[nn] = bgp[c] + blp[c];
    }
    return;
  }
  gid -= NG * KK;
  if (gid < E) atomicAdd(counts + edst[gid], 1);
}

__global__ void k_partition(const int* __restrict__ counts, int* __restrict__ row_start,
                            int* __restrict__ gcur, int n) {
  int i = blockIdx.x * blockDim.x + threadIdx.x;
  int lane = threadIdx.x & 63;
  int v = (i < n) ? counts[i] : 0;
  int s = v;
#pragma unroll
  for (int off = 1; off < 64; off <<= 1) {
    int t = __shfl_up(s, off);
    if (lane >= off) s += t;
  }
  int total = __shfl(s, 63);
  int base = 0;
  if (lane == 63) base = atomicAdd(gcur, total);
  base = __shfl(base, 63);
  if (i < n) row_start[i] = base + s - v;
}

__global__ void k_scatter(const int* __restrict__ srcv, const int* __restrict__ dstv,
                          const int* __restrict__ row_start, int* __restrict__ cursor,
                          int* __restrict__ csr, int E) {
  int e = blockIdx.x * blockDim.x + threadIdx.x;
  if (e < E) {
    int d = dstv[e];
    int pos = row_start[d] + atomicAdd(cursor + d, 1);
    csr[pos] = srcv[e];
  }
}

// One wave per node. 4 neighbor-groups x 16 lanes x bf16x8(16B) per row.
// Unconditional clamped loads, unrolled x2: 8 independent row loads + 2 csr
// index prefetches in flight per wave per iteration.
__global__ void k_agg(const unsigned short* __restrict__ hbf, const int* __restrict__ row_start,
                      const int* __restrict__ counts, const int* __restrict__ csr,
                      unsigned short* __restrict__ aggbf, int n, int mpad) {
  int wave = (blockIdx.x * blockDim.x + threadIdx.x) >> 6;
  int lane = threadIdx.x & 63;
  if (wave >= mpad) return;
  int g = lane >> 4;
  int t = lane & 15;
  float acc[8] = {0.f, 0.f, 0.f, 0.f, 0.f, 0.f, 0.f, 0.f};
  if (wave < n) {
    int s = row_start[wave], deg = counts[wave];
    if (deg > 0) {
      int e = s + deg;
      int last = e - 1;
      int jj0 = s + g;
      int jj1 = jj0 + 4;
      int src0 = csr[jj0 < last ? jj0 : last];
      int src1 = csr[jj1 < last ? jj1 : last];
      int iters = (deg + 7) >> 3;
      for (int it = 0; it < iters; ++it) {
        int jn0 = jj0 + 8, jn1 = jj1 + 8;
        int sn0 = csr[jn0 < last ? jn0 : last];
        int sn1 = csr[jn1 < last ? jn1 : last];
        bf16x8 v0 = *(const bf16x8*)(hbf + (size_t)src0 * DD + t * 8);
        bf16x8 v1 = *(const bf16x8*)(hbf + (size_t)src1 * DD + t * 8);
        float m0v = jj0 < e ? 1.f : 0.f;
        float m1v = jj1 < e ? 1.f : 0.f;
#pragma unroll
        for (int q = 0; q < 8; ++q)
          acc[q] += m0v * bf2f((unsigned short)v0[q]) + m1v * bf2f((unsigned short)v1[q]);
        jj0 = jn0; jj1 = jn1; src0 = sn0; src1 = sn1;
      }
      float inv = 1.f / (float)deg;
#pragma unroll
      for (int q = 0; q < 8; ++q) {
        acc[q] += __shfl_xor(acc[q], 16);
        acc[q] += __shfl_xor(acc[q], 32);
        acc[q] *= inv;
      }
    }
  }
  if (g == 0) {
    bf16x8 o;
#pragma unroll
    for (int q = 0; q < 8; ++q) o[q] = (short)f2bf(acc[q]);
    *(bf16x8*)(aggbf + (size_t)wave * DD + t * 8) = o;
  }
}

__device__ __forceinline__ void gload16(const void* g, void* l) {
  __builtin_amdgcn_global_load_lds((__attribute__((address_space(1))) void*)(void*)g,
                                   (__attribute__((address_space(3))) void*)l, 16, 0, 0);
}

// Fused GEMM + LSTM-gate + LayerNorm.
// BM=128, BN=512, BK=64; 1024 threads = 16 waves (2Mx8N), wave tile 64x64.
// LDS: A dbuf 2x16KB @0/16K + B dbuf 2x64KB @32K/96K = 160KB (1 block/CU).
// A(k+1) staged at STEP START into the opposite A buffer (full-step lead over
// its consumption -> covers HBM latency); B staged distance-2 after the
// mid-step lgkm barrier. Counted vmcnt; loads span raw s_barriers.
#define ABUF0 0
#define ABUF1 16384
#define BBUF0 32768
#define BBUF1 98304
__global__ __launch_bounds__(1024, 4) void k_gemm_fused(
    const unsigned short* __restrict__ hbf, const unsigned short* __restrict__ xbf,
    const unsigned short* __restrict__ aggbf, const unsigned short* __restrict__ Ut,
    const float* __restrict__ bias, const float* __restrict__ cell,
    const float* __restrict__ gamma, const float* __restrict__ beta,
    float* __restrict__ out, int nrows) {
  __shared__ char lds[163840];  // 160KB; epilogue reuses first 128KB
  const int m0 = blockIdx.x * 128;
  const int tid = threadIdx.x;
  const int w = tid >> 6, lane = tid & 63;
  const int wr = w >> 3, wc = w & 7;
  const int l15 = lane & 15, rg = lane >> 4;
  f32x4 acc[4][4] = {};

  const int srow = tid >> 3;   // 0..127 staging row
  const int sslot = tid & 7;   // 16B slot in 128B row

  auto stageA = [&](int ks) {
    const unsigned short* Ab = ks < 2 ? hbf : (ks < 4 ? xbf : aggbf);
    const int akoff = (ks & 1) * 128;
    int d = sslot ^ (srow & 7);
    gload16((const char*)Ab + (size_t)(m0 + srow) * 256 + akoff + d * 16,
            lds + ((ks & 1) ? ABUF1 : ABUF0) + tid * 16);
  };
  auto stageB = [&](int ks, int bbase) {
    const int bkoff = ks * 128;
#pragma unroll
    for (int p = 0; p < 4; ++p) {
      int r = p * 128 + srow;
      int d = sslot ^ (r & 7);
      gload16((const char*)Ut + (size_t)r * 768 + bkoff + d * 16,
              lds + bbase + p * 16384 + tid * 16);
    }
  };

  // prologue: B0, A0, B1, A1 in flight (10 loads); wait for B0+A0 (vmcnt 5)
  stageB(0, BBUF0);
  stageA(0);
  stageB(1, BBUF1);
  stageA(1);
  asm volatile("s_waitcnt vmcnt(5)" ::: "memory");
  __builtin_amdgcn_sched_barrier(0);
  __builtin_amdgcn_s_barrier();

#pragma unroll
  for (int ks = 0; ks < 6; ++ks) {
    // stage A(ks+1) into the opposite A buffer at step start: that buffer's
    // reads (step ks-1) completed before the previous mid-step barrier.
    if (ks >= 1 && ks <= 4) stageA(ks + 1);
    const char* As = lds + ((ks & 1) ? ABUF1 : ABUF0);
    const char* Bs = lds + ((ks & 1) ? BBUF1 : BBUF0);
    // ---- slice 0 ----
    bf16x8 af0[4], bq0[4];
#pragma unroll
    for (int mi = 0; mi < 4; ++mi) {
      int r = wr * 64 + mi * 16 + l15;
      af0[mi] = *(const bf16x8*)(As + r * 128 + ((rg ^ (r & 7)) * 16));
    }
#pragma unroll
    for (int ni = 0; ni < 4; ++ni) {
      int r = wc * 64 + ni * 16 + l15;
      bq0[ni] = *(const bf16x8*)(Bs + r * 128 + ((rg ^ (r & 7)) * 16));
    }
#pragma unroll
    for (int mi = 0; mi < 4; ++mi)
#pragma unroll
      for (int ni = 0; ni < 4; ++ni)
        acc[mi][ni] = __builtin_amdgcn_mfma_f32_16x16x32_bf16(af0[mi], bq0[ni], acc[mi][ni], 0, 0, 0);
    // ---- slice 1 ----
    bf16x8 af1[4], bq1[4];
#pragma unroll
    for (int mi = 0; mi < 4; ++mi) {
      int r = wr * 64 + mi * 16 + l15;
      af1[mi] = *(const bf16x8*)(As + r * 128 + (((4 + rg) ^ (r & 7)) * 16));
    }
#pragma unroll
    for (int ni = 0; ni < 4; ++ni) {
      int r = wc * 64 + ni * 16 + l15;
      bq1[ni] = *(const bf16x8*)(Bs + r * 128 + (((4 + rg) ^ (r & 7)) * 16));
    }
    // all LDS reads of this step done before anyone restages these buffers
    asm volatile("s_waitcnt lgkmcnt(0)" ::: "memory");
    __builtin_amdgcn_sched_barrier(0);
    __builtin_amdgcn_s_barrier();
    if (ks < 4) stageB(ks + 2, (ks & 1) ? BBUF1 : BBUF0);
#pragma unroll
    for (int mi = 0; mi < 4; ++mi)
#pragma unroll
      for (int ni = 0; ni < 4; ++ni)
        acc[mi][ni] = __builtin_amdgcn_mfma_f32_16x16x32_bf16(af1[mi], bq1[ni], acc[mi][ni], 0, 0, 0);
    // retire A(ks+1)+B(ks+1) (5 oldest); keep B(ks+2) in flight
    if (ks <= 3) {
      asm volatile("s_waitcnt vmcnt(4)" ::: "memory");
    } else if (ks == 4) {
      asm volatile("s_waitcnt vmcnt(0)" ::: "memory");
    }
    __builtin_amdgcn_sched_barrier(0);
    __builtin_amdgcn_s_barrier();
  }

  // stage gates (128 rows x 512 cols bf16, XOR-swizzled) into LDS[0..128KB)
  float bias_v[4];
#pragma unroll
  for (int ni = 0; ni < 4; ++ni) bias_v[ni] = bias[wc * 64 + ni * 16 + l15];
#pragma unroll
  for (int mi = 0; mi < 4; ++mi)
#pragma unroll
    for (int ni = 0; ni < 4; ++ni) {
      int col = wc * 64 + ni * 16 + l15;
#pragma unroll
      for (int j = 0; j < 4; ++j) {
        int row = wr * 64 + mi * 16 + rg * 4 + j;
        int byte = (row * 1024 + col * 2) ^ ((row & 7) << 4);
        *(unsigned short*)(lds + byte) = f2bf(acc[mi][ni][j] + bias_v[ni]);
      }
    }
  asm volatile("s_waitcnt lgkmcnt(0)" ::: "memory");
  __builtin_amdgcn_sched_barrier(0);
  __builtin_amdgcn_s_barrier();

  // full unroll: all 8 cell loads + 32 LDS reads issue together (one latency)
#pragma unroll
  for (int t = 0; t < 8; ++t) {
    int rr = w * 8 + t;
    int rowg = m0 + rr;
    if (rowg >= nrows) continue;  // wave-uniform
    int c = lane * 2;
    int sw = (rr & 7) << 4;
    ushort2 fu = *(const ushort2*)(lds + ((rr * 1024 + 0 + lane * 4) ^ sw));
    ushort2 iu = *(const ushort2*)(lds + ((rr * 1024 + 256 + lane * 4) ^ sw));
    ushort2 cu = *(const ushort2*)(lds + ((rr * 1024 + 512 + lane * 4) ^ sw));
    ushort2 ou = *(const ushort2*)(lds + ((rr * 1024 + 768 + lane * 4) ^ sw));
    float2 cv = *(const float2*)(cell + (size_t)rowg * DD + c);
    float f0 = fsigmoid(bf2f(fu.x)), f1 = fsigmoid(bf2f(fu.y));
    float i0 = fsigmoid(bf2f(iu.x)), i1 = fsigmoid(bf2f(iu.y));
    float t0 = ftanh(bf2f(cu.x)), t1 = ftanh(bf2f(cu.y));
    float o0 = fsigmoid(bf2f(ou.x)), o1 = fsigmoid(bf2f(ou.y));
    float cn0 = f0 * cv.x + i0 * t0;
    float cn1 = f1 * cv.y + i1 * t1;
    float y0 = o0 * ftanh(cn0);
    float y1 = o1 * ftanh(cn1);
    float s = y0 + y1, s2 = y0 * y0 + y1 * y1;
#pragma unroll
    for (int off = 1; off < 64; off <<= 1) {
      s += __shfl_xor(s, off);
      s2 += __shfl_xor(s2, off);
    }
    float mean = s * (1.f / 128.f);
    float var = s2 * (1.f / 128.f) - mean * mean;
    float rstd = rsqrtf(var + 1e-5f);
    float2 gm = *(const float2*)(gamma + c);
    float2 bt = *(const float2*)(beta + c);
    float h0 = (y0 - mean) * rstd * gm.x + bt.x;
    float h1 = (y1 - mean) * rstd * gm.y + bt.y;
    *(float2*)(out + (size_t)rowg * DD + c) = make_float2(h0, h1);
    *(float2*)(out + (size_t)nrows * DD + (size_t)rowg * DD + c) = make_float2(cn0, cn1);
  }
}

extern "C" void kernel_launch(void* const* d_in, const int* in_sizes, int n_in,
                              void* d_out, int out_size, void* d_ws, size_t ws_size,
                              hipStream_t stream) {
  const float* h = (const float*)d_in[0];
  const float* cellp = (const float*)d_in[1];
  const float* x = (const float*)d_in[2];
  const int* edge = (const int*)d_in[3];
  const float* Wg0 = (const float*)d_in[4];
  const float* bg0 = (const float*)d_in[5];
  const float* Wg1 = (const float*)d_in[6];
  const float* bg1 = (const float*)d_in[7];
  const float* Wg2 = (const float*)d_in[8];
  const float* bg2 = (const float*)d_in[9];
  const float* Wg3 = (const float*)d_in[10];
  const float* bg3 = (const float*)d_in[11];
  const float* Wl0 = (const float*)d_in[12];
  const float* bl0 = (const float*)d_in[13];
  const float* Wr0 = (const float*)d_in[14];
  const float* Wl1 = (const float*)d_in[15];
  const float* bl1 = (const float*)d_in[16];
  const float* Wr1 = (const float*)d_in[17];
  const float* Wl2 = (const float*)d_in[18];
  const float* bl2 = (const float*)d_in[19];
  const float* Wr2 = (const float*)d_in[20];
  const float* Wl3 = (const float*)d_in[21];
  const float* bl3 = (const float*)d_in[22];
  const float* Wr3 = (const float*)d_in[23];
  const float* gamma = (const float*)d_in[24];
  const float* beta = (const float*)d_in[25];

  int N = in_sizes[0] / DD;
  int E = in_sizes[3] / 2;
  int Mpad = ((N + 127) / 128) * 128;

  char* ws = (char*)d_ws;
  size_t off = 0;
  auto alloc = [&](size_t b) {
    char* p = ws + off;
    off += (b + 255) & ~(size_t)255;
    return p;
  };
  int* counts = (int*)alloc((size_t)N * 4);
  int* cursor = (int*)alloc((size_t)N * 4);
  int* row_start = (int*)alloc((size_t)N * 4);
  int* gcur = (int*)alloc(4);
  size_t zero_span = (size_t)((char*)gcur - (char*)counts) + 4;
  int* csr = (int*)alloc((size_t)E * 4);
  unsigned short* hbf = (unsigned short*)alloc((size_t)Mpad * DD * 2);
  unsigned short* xbf = (unsigned short*)alloc((size_t)Mpad * DD * 2);
  unsigned short* aggbf = (unsigned short*)alloc((size_t)Mpad * DD * 2);
  unsigned short* Ut = (unsigned short*)alloc((size_t)NG * KK * 2);
  float* bias = (float*)alloc((size_t)NG * 4);
  (void)ws_size;
  (void)n_in;
  (void)out_size;

  const int* esrc = edge;
  const int* edst = edge + E;

  int conv_items = Mpad * DD / 4;
  long init_total = (long)conv_items + NG * KK + E;
  int init_blocks = (int)((init_total + 255) / 256);

  hipMemsetAsync(counts, 0, zero_span, stream);
  k_init<<<init_blocks, 256, 0, stream>>>(
      h, x, hbf, xbf,
      Wg0, Wg1, Wg2, Wg3, Wl0, Wl1, Wl2, Wl3, Wr0, Wr1, Wr2, Wr3,
      bg0, bg1, bg2, bg3, bl0, bl1, bl2, bl3, Ut, bias,
      edst, counts, E, N * DD, conv_items);
  k_partition<<<(N + 255) / 256, 256, 0, stream>>>(counts, row_start, gcur, N);
  k_scatter<<<(E + 255) / 256, 256, 0, stream>>>(esrc, edst, row_start, cursor, csr, E);
  k_agg<<<Mpad / 4, 256, 0, stream>>>(hbf, row_start, counts, csr, aggbf, N, Mpad);
  k_gemm_fused<<<Mpad / 128, 1024, 0, stream>>>(hbf, xbf, aggbf, Ut, bias, cellp,
                                                gamma, beta, (float*)d_out, N);
}